// Round 2
// baseline (2580.577 us; speedup 1.0000x reference)
//
#include <hip/hip_runtime.h>
#include <hip/hip_bf16.h>
#include <math.h>

#define N_NODES 50000
#define N_EDGES 500000
#define B_GRAPHS 8
#define NPG 6250
#define HID 64
#define HO 128          // HEADS*HID
#define IN_DIM 10
#define F_TOT 266       // IN_DIM + 4*HID
#define OUT_C 532       // 2*F_TOT
#define NEG_SLOPE 0.2f
#define NT_ROWS 44      // 7 etype + 31 rid + 2 rc + 3 rp + 1 const

// dtype-agnostic float load: f32 flag chooses fp32 or bf16 interpretation
__device__ __forceinline__ float LD(const void* p, size_t i, int f32) {
    if (f32) return ((const float*)p)[i];
    unsigned u = ((const unsigned short*)p)[i];
    return __uint_as_float(u << 16);
}
// monotone float<->uint key for atomicMax on floats (memset-0 == -infinity)
__device__ __forceinline__ unsigned fkey(float f) {
    unsigned b = __float_as_uint(f);
    return (b & 0x80000000u) ? ~b : (b | 0x80000000u);
}
__device__ __forceinline__ float funkey(unsigned k) {
    unsigned b = (k & 0x80000000u) ? (k & 0x7fffffffu) : ~k;
    return __uint_as_float(b);
}

// ---------------- dtype detection ------------------------------------------
// Scan first 8192 u16 words of att_rc (N(0,1) data). Genuine bf16 never has
// exponent >= 0xC0; fp32-underlying data has ~25% of low-half words there.
__global__ void k_detect(const void* __restrict__ att_rc, int* __restrict__ flagp) {
    __shared__ int cnt;
    if (threadIdx.x == 0) cnt = 0;
    __syncthreads();
    const unsigned short* w = (const unsigned short*)att_rc;
    int c = 0;
    for (int i = threadIdx.x; i < 8192; i += 256) {
        unsigned e = (w[i] >> 7) & 0xFF;
        if (e >= 0xC0) c++;
    }
    atomicAdd(&cnt, c);
    __syncthreads();
    if (threadIdx.x == 0) *flagp = (cnt > 8) ? 1 : 0;
}

// ---------------- initial feature MLP: h = relu(feat@W0+b0)@W1+b1 ----------
__global__ void k_init(const void* __restrict__ feat,
                       const void* __restrict__ W0, const void* __restrict__ b0,
                       const void* __restrict__ W1, const void* __restrict__ b1,
                       float* __restrict__ feats, const int* __restrict__ flagp) {
    const int f32 = *flagp;
    __shared__ float sW0[IN_DIM * HID];
    __shared__ float sW1[HID * HID];
    __shared__ float sb0[HID];
    __shared__ float sb1[HID];
    for (int i = threadIdx.x; i < IN_DIM * HID; i += blockDim.x) sW0[i] = LD(W0, i, f32);
    for (int i = threadIdx.x; i < HID * HID; i += blockDim.x) sW1[i] = LD(W1, i, f32);
    for (int i = threadIdx.x; i < HID; i += blockDim.x) {
        sb0[i] = LD(b0, i, f32); sb1[i] = LD(b1, i, f32);
    }
    __syncthreads();
    int lane = threadIdx.x & 63;
    int wave = (blockIdx.x * blockDim.x + threadIdx.x) >> 6;
    int nwaves = (gridDim.x * blockDim.x) >> 6;
    for (int n = wave; n < N_NODES; n += nwaves) {
        float hid = sb0[lane];
        #pragma unroll
        for (int k = 0; k < IN_DIM; k++)
            hid += LD(feat, (size_t)n * IN_DIM + k, f32) * sW0[k * HID + lane];
        hid = fmaxf(hid, 0.f);
        float out = sb1[lane];
        for (int k = 0; k < HID; k++) {
            float hk = __shfl(hid, k, 64);
            out += hk * sW1[k * HID + lane];
        }
        float* row = feats + (size_t)n * F_TOT;
        if (lane < IN_DIM) row[lane] = LD(feat, (size_t)n * IN_DIM + lane, f32);
        row[IN_DIM + lane] = out;
    }
}

// ---------------- fused edge tables: T[l] = S @ W_fij[l] (+egat_bias) ------
__global__ void k_tables(const void* __restrict__ etype_emb, const void* __restrict__ rid_emb,
                         const void* __restrict__ rc_W, const void* __restrict__ rc_b,
                         const void* __restrict__ rp_W, const void* __restrict__ rp_b,
                         const void* __restrict__ W_fij, const void* __restrict__ egat_bias,
                         float* __restrict__ T, const int* __restrict__ flagp) {
    const int f32 = *flagp;
    int l = blockIdx.x;
    __shared__ float S[NT_ROWS * HID];   // 11 KB
    __shared__ float W[HID * HO];        // 32 KB
    for (int i = threadIdx.x; i < 7 * HID; i += 256) S[i] = LD(etype_emb, i, f32);
    for (int i = threadIdx.x; i < 31 * HID; i += 256) S[7 * HID + i] = LD(rid_emb, i, f32);
    for (int i = threadIdx.x; i < 2 * HID; i += 256) S[38 * HID + i] = LD(rc_W, i, f32);
    for (int i = threadIdx.x; i < 3 * HID; i += 256) S[40 * HID + i] = LD(rp_W, i, f32);
    for (int i = threadIdx.x; i < HID; i += 256)
        S[43 * HID + i] = LD(rc_b, i, f32) + LD(rp_b, i, f32);
    for (int i = threadIdx.x; i < HID * HO; i += 256)
        W[i] = LD(W_fij, (size_t)l * HID * HO + i, f32);
    __syncthreads();
    for (int idx = threadIdx.x; idx < NT_ROWS * HO; idx += 256) {
        int r = idx / HO, c = idx % HO;
        float acc = (r == 43) ? LD(egat_bias, l * HO + c, f32) : 0.f;
        for (int k = 0; k < HID; k++) acc += S[r * HID + k] * W[k * HO + c];
        T[(size_t)l * NT_ROWS * HO + idx] = acc;
    }
}

// ---------------- node GEMMs: f_ni/f_nj/hw = h @ {W_ni,W_nj,W_node} --------
__global__ void k_ngemm(const float* __restrict__ feats, int h_off,
                        const void* __restrict__ W_ni, const void* __restrict__ W_nj,
                        const void* __restrict__ W_node, int l,
                        float* __restrict__ f_ni, float* __restrict__ f_nj,
                        float* __restrict__ hw, const int* __restrict__ flagp) {
    const int f32 = *flagp;
    __shared__ float hs[64 * HID];   // 16 KB
    __shared__ float ws[HID * HO];   // 32 KB
    int n0 = blockIdx.x * 64;
    for (int i = threadIdx.x; i < 64 * HID; i += 256) {
        int n = n0 + i / HID;
        hs[i] = (n < N_NODES) ? feats[(size_t)n * F_TOT + h_off + (i % HID)] : 0.f;
    }
    const void* Wp[3] = {W_ni, W_nj, W_node};
    float* Op[3] = {f_ni, f_nj, hw};
    int ng = threadIdx.x / 16;   // 16 groups of 4 nodes
    int cg = threadIdx.x % 16;   // 16 groups of 8 cols
    for (int m = 0; m < 3; m++) {
        __syncthreads();
        for (int i = threadIdx.x; i < HID * HO; i += 256)
            ws[i] = LD(Wp[m], (size_t)l * HID * HO + i, f32);
        __syncthreads();
        float acc[4][8];
        #pragma unroll
        for (int i = 0; i < 4; i++)
            #pragma unroll
            for (int j = 0; j < 8; j++) acc[i][j] = 0.f;
        for (int k = 0; k < HID; k++) {
            float a[4];
            #pragma unroll
            for (int i = 0; i < 4; i++) a[i] = hs[(ng * 4 + i) * HID + k];
            #pragma unroll
            for (int j = 0; j < 8; j++) {
                float b = ws[k * HO + cg * 8 + j];
                #pragma unroll
                for (int i = 0; i < 4; i++) acc[i][j] += a[i] * b;
            }
        }
        #pragma unroll
        for (int i = 0; i < 4; i++) {
            int n = n0 + ng * 4 + i;
            if (n < N_NODES) {
                #pragma unroll
                for (int j = 0; j < 8; j++)
                    Op[m][(size_t)n * HO + cg * 8 + j] = acc[i][j];
            }
        }
    }
}

// ---------------- edge logits e + segment max ------------------------------
__global__ void k_edge_e(const float* __restrict__ T, const void* __restrict__ attn, int l,
                         const float* __restrict__ f_ni, const float* __restrict__ f_nj,
                         const int* __restrict__ src, const int* __restrict__ dst,
                         const int* __restrict__ etype, const int* __restrict__ rid,
                         const void* __restrict__ att_rc, const void* __restrict__ att_rp,
                         float* __restrict__ e_buf, unsigned* __restrict__ mkey,
                         const int* __restrict__ flagp) {
    const int f32 = *flagp;
    __shared__ float Ts[NT_ROWS * HO];   // 22 KB
    __shared__ float at[HO];
    for (int i = threadIdx.x; i < NT_ROWS * HO; i += 256) Ts[i] = T[(size_t)l * NT_ROWS * HO + i];
    for (int i = threadIdx.x; i < HO; i += 256) at[i] = LD(attn, l * HO + i, f32);
    __syncthreads();
    int lane = threadIdx.x & 63;
    int wave = (blockIdx.x * blockDim.x + threadIdx.x) >> 6;
    int nw = (gridDim.x * blockDim.x) >> 6;
    for (int e = wave; e < N_EDGES; e += nw) {
        int s = src[e], d = dst[e], et = etype[e], ri = rid[e];
        float rc0 = LD(att_rc, 2 * (size_t)e, f32), rc1 = LD(att_rc, 2 * (size_t)e + 1, f32);
        float rp0 = LD(att_rp, 3 * (size_t)e, f32), rp1 = LD(att_rp, 3 * (size_t)e + 1, f32),
              rp2 = LD(att_rp, 3 * (size_t)e + 2, f32);
        float p0, p1;
        {
            int c = lane;
            float fij = Ts[et * HO + c] + Ts[(7 + ri) * HO + c]
                      + rc0 * Ts[38 * HO + c] + rc1 * Ts[39 * HO + c]
                      + rp0 * Ts[40 * HO + c] + rp1 * Ts[41 * HO + c] + rp2 * Ts[42 * HO + c]
                      + Ts[43 * HO + c];
            float x = f_ni[(size_t)s * HO + c] + f_nj[(size_t)d * HO + c] + fij;
            x = (x > 0.f) ? x : NEG_SLOPE * x;
            p0 = x * at[c];
        }
        {
            int c = 64 + lane;
            float fij = Ts[et * HO + c] + Ts[(7 + ri) * HO + c]
                      + rc0 * Ts[38 * HO + c] + rc1 * Ts[39 * HO + c]
                      + rp0 * Ts[40 * HO + c] + rp1 * Ts[41 * HO + c] + rp2 * Ts[42 * HO + c]
                      + Ts[43 * HO + c];
            float x = f_ni[(size_t)s * HO + c] + f_nj[(size_t)d * HO + c] + fij;
            x = (x > 0.f) ? x : NEG_SLOPE * x;
            p1 = x * at[c];
        }
        #pragma unroll
        for (int off = 32; off; off >>= 1) {
            p0 += __shfl_xor(p0, off, 64);
            p1 += __shfl_xor(p1, off, 64);
        }
        if (lane == 0) {
            e_buf[2 * (size_t)e] = p0;
            e_buf[2 * (size_t)e + 1] = p1;
            atomicMax(&mkey[2 * d], fkey(p0));
            atomicMax(&mkey[2 * d + 1], fkey(p1));
        }
    }
}

// ---------------- exp(e - max) + segment sum -------------------------------
__global__ void k_edge_sm(const int* __restrict__ dst, const unsigned* __restrict__ mkey,
                          float* __restrict__ e_buf, float* __restrict__ ssum) {
    int i = blockIdx.x * blockDim.x + threadIdx.x;
    int stride = gridDim.x * blockDim.x;
    for (int e = i; e < N_EDGES; e += stride) {
        int d = dst[e];
        float m0 = funkey(mkey[2 * d]), m1 = funkey(mkey[2 * d + 1]);
        float x0 = expf(e_buf[2 * (size_t)e] - m0);
        float x1 = expf(e_buf[2 * (size_t)e + 1] - m1);
        e_buf[2 * (size_t)e] = x0;
        e_buf[2 * (size_t)e + 1] = x1;
        atomicAdd(&ssum[2 * d], x0);
        atomicAdd(&ssum[2 * d + 1], x1);
    }
}

// ---------------- message scatter: h_att[dst] += alpha * hw[src] -----------
__global__ void k_edge_msg(const int* __restrict__ src, const int* __restrict__ dst,
                           const float* __restrict__ e_buf, const float* __restrict__ ssum,
                           const float* __restrict__ hw, float* __restrict__ h_att) {
    int lane = threadIdx.x & 63;
    int wave = (blockIdx.x * blockDim.x + threadIdx.x) >> 6;
    int nw = (gridDim.x * blockDim.x) >> 6;
    for (int e = wave; e < N_EDGES; e += nw) {
        int s = src[e], d = dst[e];
        float a0 = e_buf[2 * (size_t)e] / (ssum[2 * d] + 1e-9f);
        float a1 = e_buf[2 * (size_t)e + 1] / (ssum[2 * d + 1] + 1e-9f);
        atomicAdd(&h_att[(size_t)d * HO + lane], a0 * hw[(size_t)s * HO + lane]);
        atomicAdd(&h_att[(size_t)d * HO + 64 + lane], a1 * hw[(size_t)s * HO + 64 + lane]);
    }
}

// ---------------- node MLP + residual: h_new = MLP2(h_att) + h_prev --------
__global__ void k_mlp(const float* __restrict__ h_att,
                      const void* __restrict__ Wm0, const void* __restrict__ bm0,
                      const void* __restrict__ Wm1, const void* __restrict__ bm1, int l,
                      float* __restrict__ feats, int prev_off, int out_off,
                      const int* __restrict__ flagp) {
    const int f32 = *flagp;
    __shared__ float xs[32 * HO];   // 16 KB
    __shared__ float ys[32 * HO];   // 16 KB
    __shared__ float ws[HO * 64];   // 32 KB
    int n0 = blockIdx.x * 32;
    for (int i = threadIdx.x; i < 32 * HO; i += 256) {
        int n = n0 + i / HO;
        xs[i] = (n < N_NODES) ? h_att[(size_t)n * HO + (i % HO)] : 0.f;
    }
    int ng = threadIdx.x / 16;   // 16 groups of 2 nodes
    int cg = threadIdx.x % 16;   // 16 groups of 4 cols
    // stage A: ys = relu(xs @ Wm0 + bm0), in two 64-col halves
    for (int ch = 0; ch < 2; ch++) {
        __syncthreads();
        for (int i = threadIdx.x; i < HO * 64; i += 256) {
            int k = i / 64, c = i % 64;
            ws[i] = LD(Wm0, (size_t)l * HO * HO + k * HO + ch * 64 + c, f32);
        }
        __syncthreads();
        float acc[2][4];
        #pragma unroll
        for (int i = 0; i < 2; i++)
            #pragma unroll
            for (int j = 0; j < 4; j++)
                acc[i][j] = LD(bm0, l * HO + ch * 64 + cg * 4 + j, f32);
        for (int k = 0; k < HO; k++) {
            float a0 = xs[(ng * 2 + 0) * HO + k];
            float a1 = xs[(ng * 2 + 1) * HO + k];
            #pragma unroll
            for (int j = 0; j < 4; j++) {
                float b = ws[k * 64 + cg * 4 + j];
                acc[0][j] += a0 * b;
                acc[1][j] += a1 * b;
            }
        }
        #pragma unroll
        for (int i = 0; i < 2; i++)
            #pragma unroll
            for (int j = 0; j < 4; j++)
                ys[(ng * 2 + i) * HO + ch * 64 + cg * 4 + j] = fmaxf(acc[i][j], 0.f);
    }
    __syncthreads();
    // stage B: h = ys @ Wm1 + bm1 + prev
    for (int i = threadIdx.x; i < HO * 64; i += 256)
        ws[i] = LD(Wm1, (size_t)l * HO * 64 + i, f32);
    __syncthreads();
    float acc[2][4];
    #pragma unroll
    for (int i = 0; i < 2; i++)
        #pragma unroll
        for (int j = 0; j < 4; j++) acc[i][j] = LD(bm1, l * 64 + cg * 4 + j, f32);
    for (int k = 0; k < HO; k++) {
        float a0 = ys[(ng * 2 + 0) * HO + k];
        float a1 = ys[(ng * 2 + 1) * HO + k];
        #pragma unroll
        for (int j = 0; j < 4; j++) {
            float b = ws[k * 64 + cg * 4 + j];
            acc[0][j] += a0 * b;
            acc[1][j] += a1 * b;
        }
    }
    #pragma unroll
    for (int i = 0; i < 2; i++) {
        int n = n0 + ng * 2 + i;
        if (n < N_NODES) {
            float* r = feats + (size_t)n * F_TOT;
            #pragma unroll
            for (int j = 0; j < 4; j++)
                r[out_off + cg * 4 + j] = acc[i][j] + r[prev_off + cg * 4 + j];
        }
    }
}

// ---------------- graph max pool -------------------------------------------
__global__ void k_pool(const float* __restrict__ feats, unsigned* __restrict__ gmax) {
    int g = blockIdx.x;
    int chunk = blockIdx.y;
    int t = threadIdx.x;
    const int CS = (NPG + 15) / 16;   // 391
    int nb = chunk * CS;
    int ne = (nb + CS < NPG) ? nb + CS : NPG;
    float m0 = -INFINITY, m1 = -INFINITY;
    for (int n = nb; n < ne; n++) {
        const float* row = feats + (size_t)(g * NPG + n) * F_TOT;
        m0 = fmaxf(m0, row[t]);
        if (t + 256 < F_TOT) m1 = fmaxf(m1, row[t + 256]);
    }
    atomicMax(&gmax[g * F_TOT + t], fkey(m0));
    if (t + 256 < F_TOT) atomicMax(&gmax[g * F_TOT + t + 256], fkey(m1));
}

// ---------------- output write: [features | broadcast graph-max] -----------
__global__ void k_out(const float* __restrict__ feats, const unsigned* __restrict__ gmax,
                      void* __restrict__ out, const int* __restrict__ flagp) {
    const int f32 = *flagp;
    size_t total = (size_t)B_GRAPHS * NPG * OUT_C;
    size_t stride = (size_t)gridDim.x * blockDim.x;
    for (size_t i = (size_t)blockIdx.x * blockDim.x + threadIdx.x; i < total; i += stride) {
        int c = (int)(i % OUT_C);
        size_t gn = i / OUT_C;
        int g = (int)(gn / NPG);
        float v = (c < F_TOT) ? feats[gn * F_TOT + c] : funkey(gmax[g * F_TOT + (c - F_TOT)]);
        if (f32) ((float*)out)[i] = v;
        else ((__hip_bfloat16*)out)[i] = __float2bfloat16(v);
    }
}

extern "C" void kernel_launch(void* const* d_in, const int* in_sizes, int n_in,
                              void* d_out, int out_size, void* d_ws, size_t ws_size,
                              hipStream_t stream) {
    const void* feat      = d_in[0];
    const void* att_rc    = d_in[1];
    const void* att_rp    = d_in[2];
    const void* etype_emb = d_in[3];
    const void* rid_emb   = d_in[4];
    const void* rc_W      = d_in[5];
    const void* rc_b      = d_in[6];
    const void* rp_W      = d_in[7];
    const void* rp_b      = d_in[8];
    const void* fe_W0     = d_in[9];
    const void* fe_b0     = d_in[10];
    const void* fe_W1     = d_in[11];
    const void* fe_b1     = d_in[12];
    const void* W_ni      = d_in[13];
    const void* W_nj      = d_in[14];
    const void* W_fij     = d_in[15];
    const void* W_node    = d_in[16];
    const void* attn      = d_in[17];
    const void* egat_bias = d_in[18];
    const void* Wm0       = d_in[19];
    const void* bm0       = d_in[20];
    const void* Wm1       = d_in[21];
    const void* bm1       = d_in[22];
    const int* src   = (const int*)d_in[23];
    const int* dst   = (const int*)d_in[24];
    const int* etype = (const int*)d_in[25];
    const int* rid   = (const int*)d_in[26];

    char* p = (char*)d_ws;
    auto alloc = [&](size_t bytes) {
        char* r = p;
        p += (bytes + 255) & ~(size_t)255;
        return r;
    };
    float*    feats = (float*)alloc((size_t)N_NODES * F_TOT * 4);   // 53.2 MB
    float*    f_ni  = (float*)alloc((size_t)N_NODES * HO * 4);      // 25.6 MB
    float*    f_nj  = (float*)alloc((size_t)N_NODES * HO * 4);      // 25.6 MB
    float*    hw    = (float*)alloc((size_t)N_NODES * HO * 4);      // 25.6 MB
    float*    h_att = (float*)alloc((size_t)N_NODES * HO * 4);      // 25.6 MB
    float*    e_buf = (float*)alloc((size_t)N_EDGES * 2 * 4);       // 4 MB
    unsigned* mkey  = (unsigned*)alloc((size_t)N_NODES * 2 * 4);
    float*    ssum  = (float*)alloc((size_t)N_NODES * 2 * 4);
    float*    T     = (float*)alloc((size_t)3 * NT_ROWS * HO * 4);
    unsigned* gmax  = (unsigned*)alloc((size_t)B_GRAPHS * F_TOT * 4);
    int*      flagp = (int*)alloc(256);

    k_detect<<<1, 256, 0, stream>>>(att_rc, flagp);
    hipMemsetAsync(gmax, 0, (size_t)B_GRAPHS * F_TOT * 4, stream);
    k_init<<<512, 256, 0, stream>>>(feat, fe_W0, fe_b0, fe_W1, fe_b1, feats, flagp);
    k_tables<<<3, 256, 0, stream>>>(etype_emb, rid_emb, rc_W, rc_b, rp_W, rp_b,
                                    W_fij, egat_bias, T, flagp);
    for (int l = 0; l < 3; l++) {
        int h_off = IN_DIM + l * HID;
        int out_off = IN_DIM + (l + 1) * HID;
        hipMemsetAsync(mkey, 0, (size_t)N_NODES * 2 * 4, stream);
        hipMemsetAsync(ssum, 0, (size_t)N_NODES * 2 * 4, stream);
        hipMemsetAsync(h_att, 0, (size_t)N_NODES * HO * 4, stream);
        k_ngemm<<<(N_NODES + 63) / 64, 256, 0, stream>>>(feats, h_off, W_ni, W_nj, W_node, l,
                                                         f_ni, f_nj, hw, flagp);
        k_edge_e<<<1024, 256, 0, stream>>>(T, attn, l, f_ni, f_nj, src, dst, etype, rid,
                                           att_rc, att_rp, e_buf, mkey, flagp);
        k_edge_sm<<<512, 256, 0, stream>>>(dst, mkey, e_buf, ssum);
        k_edge_msg<<<2048, 256, 0, stream>>>(src, dst, e_buf, ssum, hw, h_att);
        k_mlp<<<(N_NODES + 31) / 32, 256, 0, stream>>>(h_att, Wm0, bm0, Wm1, bm1, l,
                                                       feats, h_off, out_off, flagp);
    }
    k_pool<<<dim3(B_GRAPHS, 16), 256, 0, stream>>>(feats, gmax);
    k_out<<<4096, 256, 0, stream>>>(feats, gmax, d_out, flagp);
}